// Round 1
// baseline (894.009 us; speedup 1.0000x reference)
//
#include <hip/hip_runtime.h>

// Problem constants (from reference): B=4, L=4096, V=8192.
#define BB 4
#define LL 4096
#define VV 8192
#define SIGMA_SCALE 0.01f

// out[b,l,v] = W[v, idx[b,l]] + 0.01*sigma[b]*rowsum(W)[v] + bias[v]
// (one_hot @ W.T gathers COLUMN idx of W; col_sum in the reference is
//  jnp.sum(W, axis=1) == per-row sum of W.)

// ---------------------------------------------------------------------------
// Kernel 1: per-row sum of W, fused into the per-(b,v) additive table:
//   add[b*V + v] = SIGMA_SCALE * sigma[b] * sum_j W[v,j] + bias[v]
// One block (256 threads) per row v; float4 coalesced reads.
__global__ void rowsum_kernel(const float* __restrict__ W,
                              const float* __restrict__ sigma,
                              const float* __restrict__ bias,
                              float* __restrict__ add) {
    __shared__ float red[256];
    const int v = blockIdx.x;
    const float4* row4 = (const float4*)(W + (size_t)v * VV);
    float s = 0.f;
#pragma unroll
    for (int j = threadIdx.x; j < VV / 4; j += 256) {
        float4 x = row4[j];
        s += x.x + x.y + x.z + x.w;
    }
    red[threadIdx.x] = s;
    __syncthreads();
    for (int off = 128; off > 0; off >>= 1) {
        if (threadIdx.x < off) red[threadIdx.x] += red[threadIdx.x + off];
        __syncthreads();
    }
    if (threadIdx.x < BB) {
        add[threadIdx.x * VV + v] =
            SIGMA_SCALE * sigma[threadIdx.x] * red[0] + bias[v];
    }
}

// ---------------------------------------------------------------------------
// Kernel 2: tiled transpose W[v,c] -> WT[c,v]. 64x64 tile, LDS pad +1.
// block dim (64,4); both global read and write are lane-contiguous.
__global__ void transpose_kernel(const float* __restrict__ W,
                                 float* __restrict__ WT) {
    __shared__ float tile[64][65];
    const int c0 = blockIdx.x * 64;
    const int v0 = blockIdx.y * 64;
    const int tx = threadIdx.x;  // 0..63
    const int ty = threadIdx.y;  // 0..3
#pragma unroll
    for (int k = 0; k < 16; ++k) {
        tile[ty + 4 * k][tx] = W[(size_t)(v0 + ty + 4 * k) * VV + c0 + tx];
    }
    __syncthreads();
#pragma unroll
    for (int k = 0; k < 16; ++k) {
        WT[(size_t)(c0 + ty + 4 * k) * VV + v0 + tx] = tile[tx][ty + 4 * k];
    }
}

// ---------------------------------------------------------------------------
// Kernel 3: per-token row gather, fully coalesced float4.
// out[n, :] = WT[idx[n], :] + add[b(n), :]
__global__ void gather_kernel(const int* __restrict__ idx,
                              const float* __restrict__ WT,
                              const float* __restrict__ add,
                              float* __restrict__ out) {
    const int n = blockIdx.x;
    const int b = n >> 12;  // n / LL
    int c = idx[n];
    c = min(max(c, 0), VV - 1);
    const float4* src = (const float4*)(WT + (size_t)c * VV);
    const float4* av = (const float4*)(add + (size_t)b * VV);
    float4* dst = (float4*)(out + (size_t)n * VV);
#pragma unroll
    for (int i = threadIdx.x; i < VV / 4; i += 256) {
        float4 s = src[i];
        float4 a = av[i];
        dst[i] = make_float4(s.x + a.x, s.y + a.y, s.z + a.z, s.w + a.w);
    }
}

// ---------------------------------------------------------------------------
// Fallback (workspace too small for WT): direct strided column gather.
// Correct but uncoalesced on the W read; only used if ws_size is tiny.
__global__ void gather_direct_kernel(const int* __restrict__ idx,
                                     const float* __restrict__ W,
                                     const float* __restrict__ add,
                                     float* __restrict__ out) {
    const int n = blockIdx.x;
    const int b = n >> 12;
    int c = idx[n];
    c = min(max(c, 0), VV - 1);
    const int v0 = blockIdx.y * (VV / 4);
    for (int v = v0 + threadIdx.x; v < v0 + VV / 4; v += 256) {
        out[(size_t)n * VV + v] = W[(size_t)v * VV + c] + add[b * VV + v];
    }
}

extern "C" void kernel_launch(void* const* d_in, const int* in_sizes, int n_in,
                              void* d_out, int out_size, void* d_ws,
                              size_t ws_size, hipStream_t stream) {
    const int* indices = (const int*)d_in[0];   // [B, L] int32
    const float* sigma = (const float*)d_in[1]; // [B]
    const float* W = (const float*)d_in[2];     // [V, V]
    const float* bias = (const float*)d_in[3];  // [V]
    float* out = (float*)d_out;                 // [B, L, V]

    float* add = (float*)d_ws;  // B*V floats = 128 KB
    const size_t add_bytes = (size_t)BB * VV * sizeof(float);
    float* WT = (float*)((char*)d_ws + add_bytes);
    const size_t wt_bytes = (size_t)VV * VV * sizeof(float);

    rowsum_kernel<<<VV, 256, 0, stream>>>(W, sigma, bias, add);

    if (ws_size >= add_bytes + wt_bytes) {
        transpose_kernel<<<dim3(VV / 64, VV / 64), dim3(64, 4), 0, stream>>>(W, WT);
        gather_kernel<<<BB * LL, 256, 0, stream>>>(indices, WT, add, out);
    } else {
        gather_direct_kernel<<<dim3(BB * LL, 4), 256, 0, stream>>>(indices, W, add, out);
    }
}